// Round 6
// baseline (3570.486 us; speedup 1.0000x reference)
//
#include <hip/hip_runtime.h>

typedef __attribute__((ext_vector_type(8))) short short8;   // 8 bf16 = 4 VGPRs (MFMA A/B frag)
typedef __attribute__((ext_vector_type(4))) float f32x4;    // MFMA C/D frag

#define F   256
#define SH  264   // LDS row stride in bf16 units: 528 B, 16B-aligned, <=2-way bank aliasing

__device__ __forceinline__ short f2bf(float f) {
    union { float f; unsigned u; } v; v.f = f;
    unsigned r = (v.u + 0x7fffu + ((v.u >> 16) & 1u)) >> 16;   // RTNE
    return (short)r;
}
__device__ __forceinline__ float bf2f(short s) {
    union { float f; unsigned u; } v; v.u = ((unsigned)(unsigned short)s) << 16;
    return v.f;
}
__device__ __forceinline__ float sigm(float x) {
    return __builtin_amdgcn_rcpf(1.f + __builtin_amdgcn_exp2f(-1.442695041f * x));
}
__device__ __forceinline__ float tanhx(float x) {
    return 1.f - 2.f * __builtin_amdgcn_rcpf(1.f + __builtin_amdgcn_exp2f(2.885390082f * x));
}
__device__ __forceinline__ f32x4 splat4(float v) {
    f32x4 r; r[0] = v; r[1] = v; r[2] = v; r[3] = v; return r;
}

// ---------------------------------------------------------------------------
// Pack: whh/wih (hi+lo split) in COL-BLOCK-SLICED MFMA-B order (R3 layout,
// proven): dst = c*32768 + ((i*8+kt)*512 + lane*8), i = 2*gate + s, where
// n-tile nt -> gate = nt>>4, c = (nt&15)>>1, s = nt&1.
// wout in wave-contiguous order (R5 layout, proven):
// dst = ((w*8+kt)*2 + s)*512 + lane*8, nt = 2w + s.
// Zeroes the 32 per-row-group exchange counters.
// ---------------------------------------------------------------------------
__global__ void pack_kernel(const float* __restrict__ Whh, const float* __restrict__ Wih,
                            const float* __restrict__ Wout,
                            short* __restrict__ whh_p, short* __restrict__ wih_hi,
                            short* __restrict__ wih_lo, short* __restrict__ wout_p,
                            unsigned* __restrict__ ctr)
{
    int idx = blockIdx.x * blockDim.x + threadIdx.x;
    if (idx < 64) ctr[idx] = 0u;
    if (idx < 64 * 8 * 64) {                       // W_hh + W_ih: 64 n-tiles x 8 kt x 64 lanes
        int lane = idx & 63, kt = (idx >> 6) & 7, nt = idx >> 9;
        int n = nt * 16 + (lane & 15);
        int k = kt * 32 + (lane >> 4) * 8;
        int c = (nt & 15) >> 1;
        int i = ((nt >> 4) << 1) | (nt & 1);
        int dst = c * 32768 + ((i * 8 + kt) * 512 + lane * 8);
        const float* s1 = Whh + n * F + k;
        const float* s2 = Wih + n * F + k;
        #pragma unroll
        for (int j = 0; j < 8; j++) {
            whh_p[dst + j] = f2bf(s1[j]);
            float v = s2[j];
            short hi = f2bf(v);
            wih_hi[dst + j] = hi;
            wih_lo[dst + j] = f2bf(v - bf2f(hi));
        }
    } else {
        int i2 = idx - 64 * 8 * 64;
        if (i2 < 16 * 8 * 64) {                    // W_out: 16 n-tiles
            int lane = i2 & 63, kt = (i2 >> 6) & 7, nt = i2 >> 9;
            int n = nt * 16 + (lane & 15);
            int k = kt * 32 + (lane >> 4) * 8;
            int w = nt >> 1, s = nt & 1;
            int dst = (((w * 8 + kt) * 2 + s) * 64 + lane) * 8;
            const float* sp = Wout + n * F + k;
            #pragma unroll
            for (int j = 0; j < 8; j++) wout_p[dst + j] = f2bf(sp[j]);
        }
    }
}

// Load a wave's 32 B-fragments (4 gates x 8 kt, its cw half of 32 cols).
__device__ __forceinline__ void load_wb(short8 (&wb)[4][8], const short* __restrict__ base,
                                        int cw, int lane)
{
    #pragma unroll
    for (int g = 0; g < 4; g++)
        #pragma unroll
        for (int kt = 0; kt < 8; kt++)
            wb[g][kt] = *(const short8*)(base + (((2 * g + cw) * 8 + kt) * 512 + lane * 8));
}

// acc[g][mt] += A(rows rw*32 + mt*16, from LDS) x wb[g][kt] over K=256.
__device__ __forceinline__ void mm_reg(f32x4 (&acc)[4][2], const short8 (&wb)[4][8],
                                       const short* hb, int rw, int l15, int quad)
{
    #pragma unroll
    for (int kt = 0; kt < 8; kt++) {
        short8 a0 = *(const short8*)(hb + (rw * 32 + l15) * SH + kt * 32 + quad * 8);
        short8 a1 = *(const short8*)(hb + (rw * 32 + 16 + l15) * SH + kt * 32 + quad * 8);
        #pragma unroll
        for (int g = 0; g < 4; g++) {
            acc[g][0] = __builtin_amdgcn_mfma_f32_16x16x32_bf16(a0, wb[g][kt], acc[g][0], 0, 0, 0);
            acc[g][1] = __builtin_amdgcn_mfma_f32_16x16x32_bf16(a1, wb[g][kt], acc[g][1], 0, 0, 0);
        }
    }
}

// ---------------------------------------------------------------------------
// Weights-stationary recurrence.  256 blocks (1/CU, co-resident; LDS 84 KB
// forces 1/CU) = 32 row-groups x 8 col-blocks.  Block (rg,c): 128 rows x
// 32 h-cols.  W_hh slice pinned in VGPRs via asm (128 VGPRs) for all T steps
// -> ZERO steady-state weight traffic.  Per step: h chunk -> G history slot
// (NT), release fence + group counter, bounded spin, acquire fence, wide
// read-back of the full 256-col slice.  G doubles as hs history for out_proj.
// ---------------------------------------------------------------------------
__global__ __launch_bounds__(512, 2)
void lstm_rec(const float* __restrict__ x, const float* __restrict__ b_ih,
              const float* __restrict__ b_hh, const float* __restrict__ c0,
              const short* __restrict__ whh_p, const short* __restrict__ wih_hi,
              const short* __restrict__ wih_lo, const int* __restrict__ seqlen,
              unsigned* __restrict__ ctr, short* __restrict__ G)
{
    __shared__ short hbuf[128 * SH];     // 67.6 KB: row-group's full h (128 x 256)
    __shared__ short hstage[128 * 32];   //  8.2 KB: own h chunk, row-major
    __shared__ short lds_pad[4096];      //  8.2 KB: total 84 KB -> 1 block/CU always
    const int T    = *seqlen;
    const int tid  = threadIdx.x;
    const int lane = tid & 63;
    const int wv   = tid >> 6;           // wave 0..7
    const int rw   = wv >> 1;            // row-wave 0..3 (32 rows each)
    const int cw   = wv & 1;             // col-wave 0..1 (16 h-cols each)
    const int l15  = lane & 15;
    const int quad = lane >> 4;
    const int c    = blockIdx.x & 7;     // col-block 0..7
    const int rg   = blockIdx.x >> 3;    // row-group 0..31
    const int row0 = rg * 128;

    if (T == -2147483647) ((volatile short*)lds_pad)[tid] = 0;   // keep pad allocated

    // staging geometry (R3, proven): thread covers row xr, 4-elem col chunks
    const int xr = tid >> 2;             // 0..127
    const int xq = (tid & 3) * 4;

    // ---- x_proj = x @ W_ih^T (+biases), fp32-exact via 3-term split bf16 ----
    f32x4 xpj[4][2];
    #pragma unroll
    for (int g = 0; g < 4; g++) { xpj[g][0] = splat4(0.f); xpj[g][1] = splat4(0.f); }

    short8 wb[4][8];

    {   // stage x_lo
        const float* xp = x + (size_t)(row0 + xr) * F;
        #pragma unroll
        for (int j = 0; j < 16; j++) {
            f32x4 v = *(const f32x4*)(xp + xq + j * 16);
            #pragma unroll
            for (int e = 0; e < 4; e++) {
                short hi = f2bf(v[e]);
                hbuf[xr * SH + xq + j * 16 + e] = f2bf(v[e] - bf2f(hi));
            }
        }
    }
    load_wb(wb, wih_hi + c * 32768, cw, lane);
    __syncthreads();
    mm_reg(xpj, wb, hbuf, rw, l15, quad);          // x_lo x Wih_hi
    __syncthreads();
    {   // stage x_hi (stays as h_0)
        const float* xp = x + (size_t)(row0 + xr) * F;
        #pragma unroll
        for (int j = 0; j < 16; j++) {
            f32x4 v = *(const f32x4*)(xp + xq + j * 16);
            #pragma unroll
            for (int e = 0; e < 4; e++)
                hbuf[xr * SH + xq + j * 16 + e] = f2bf(v[e]);
        }
    }
    __syncthreads();
    mm_reg(xpj, wb, hbuf, rw, l15, quad);          // x_hi x Wih_hi
    load_wb(wb, wih_lo + c * 32768, cw, lane);
    mm_reg(xpj, wb, hbuf, rw, l15, quad);          // x_hi x Wih_lo

    // ---- persistent W_hh fragments, pinned in VGPRs ----
    load_wb(wb, whh_p + c * 32768, cw, lane);
    #pragma unroll
    for (int g = 0; g < 4; g++)
        #pragma unroll
        for (int kt = 0; kt < 8; kt++)
            asm volatile("" : "+v"(wb[g][kt]));    // pin: asm is now the definer

    // biases (b_ih + b_hh), per gate column
    const int mycol = c * 32 + cw * 16 + l15;
    #pragma unroll
    for (int g = 0; g < 4; g++) {
        float bias = b_ih[g * 256 + mycol] + b_hh[g * 256 + mycol];
        #pragma unroll
        for (int mt = 0; mt < 2; mt++)
            #pragma unroll
            for (int r = 0; r < 4; r++) xpj[g][mt][r] += bias;
    }

    // cell state init (c0 broadcast over rows)
    float cst[2][4];
    {
        float cv = c0[mycol];
        #pragma unroll
        for (int mt = 0; mt < 2; mt++)
            #pragma unroll
            for (int r = 0; r < 4; r++) cst[mt][r] = cv;
    }

    const int grow = tid >> 2;           // G dump/read geometry
    const int gch  = tid & 3;

    for (int t = 0; t < T; t++) {
        // gates = x_proj + h_t @ W_hh^T  (B from pinned regs, A from LDS)
        f32x4 acc[4][2];
        #pragma unroll
        for (int g = 0; g < 4; g++) { acc[g][0] = xpj[g][0]; acc[g][1] = xpj[g][1]; }
        mm_reg(acc, wb, hbuf, rw, l15, quad);

        // cell update (fp32); own h chunk -> hstage (row-major 128x32)
        #pragma unroll
        for (int mt = 0; mt < 2; mt++)
          #pragma unroll
          for (int r = 0; r < 4; r++) {
            float ig = sigm(acc[0][mt][r]);
            float fg = sigm(acc[1][mt][r]);
            float gg = tanhx(acc[2][mt][r]);
            float og = sigm(acc[3][mt][r]);
            float cn = fg * cst[mt][r] + ig * gg;
            cst[mt][r] = cn;
            hstage[(rw * 32 + mt * 16 + quad * 4 + r) * 32 + cw * 16 + l15]
                = f2bf(og * tanhx(cn));
          }
        __syncthreads();   // hstage complete; all waves done reading hbuf

        // dump chunk -> G[(row*T + t)*256 + c*32 ...], 16B NT stores
        {
            short8 v = *(const short8*)(hstage + grow * 32 + gch * 8);
            __builtin_nontemporal_store(
                v, (short8*)(G + ((size_t)(row0 + grow) * T + t) * F + c * 32 + gch * 8));
        }
        __builtin_amdgcn_fence(__ATOMIC_RELEASE, "agent");
        __syncthreads();

        // group barrier: 8 col-blocks of this row-group (monotonic, bounded)
        if (tid == 0) {
            __hip_atomic_fetch_add(&ctr[rg], 1u, __ATOMIC_RELAXED,
                                   __HIP_MEMORY_SCOPE_AGENT);
            unsigned tgt = 8u * (unsigned)(t + 1);
            int guard = 1 << 18;
            while (__hip_atomic_load(&ctr[rg], __ATOMIC_RELAXED,
                                     __HIP_MEMORY_SCOPE_AGENT) < tgt && --guard)
                __builtin_amdgcn_s_sleep(1);
        }
        __syncthreads();
        __builtin_amdgcn_fence(__ATOMIC_ACQUIRE, "agent");

        // read back full 256-col slice of h_{t+1} -> hbuf (8 x 16B per thread)
        {
            const short* gp = G + ((size_t)(row0 + grow) * T + t) * F;
            #pragma unroll
            for (int k = 0; k < 8; k++) {
                short8 v = *(const short8*)(gp + (gch * 8 + k) * 8);
                *(short8*)(hbuf + grow * SH + (gch * 8 + k) * 8) = v;
            }
        }
        __syncthreads();
    }
}

// ---------------------------------------------------------------------------
// Phase 2: out[M,256] = G[M,256](bf16) @ W_out^T + b_out, M = 4096*T.
// W_out frags in registers; result transposed through LDS so global stores
// are full 1 KB rows of NT dwordx4.
// ---------------------------------------------------------------------------
#define OSTR 264
__global__ __launch_bounds__(512, 4)
void out_proj(const short* __restrict__ G, const short* __restrict__ wout_p,
              const float* __restrict__ b_out, const int* __restrict__ seqlen,
              float* __restrict__ out)
{
    __shared__ short abuf[32 * SH];      // 16.9 KB
    __shared__ float obuf[32 * OSTR];    // 33.8 KB
    const int M    = 4096 * (*seqlen);
    const int tid  = threadIdx.x;
    const int lane = tid & 63;
    const int w    = tid >> 6;
    const int l15  = lane & 15;
    const int quad = lane >> 4;
    const int xr   = tid >> 4;          // 0..31
    const int xc   = (tid & 15) * 16;   // 0..240 (shorts)

    // wave's W_out fragments (cols w*32 .. w*32+31): 2 n-subtiles x 8 kt
    short8 wb[2][8];
    #pragma unroll
    for (int s = 0; s < 2; s++)
        #pragma unroll
        for (int kt = 0; kt < 8; kt++)
            wb[s][kt] = *(const short8*)(wout_p + w * 8192 + kt * 1024 + s * 512 + lane * 8);

    float bo[2] = { b_out[w * 32 + l15], b_out[w * 32 + 16 + l15] };

    for (int ch = blockIdx.x; ch * 32 < M; ch += gridDim.x) {
        const int m0 = ch * 32;
        // stage 32 rows of G -> LDS (coalesced 16B loads)
        const short* gp = G + (size_t)(m0 + xr) * F + xc;
        *(short8*)(abuf + xr * SH + xc)     = *(const short8*)(gp);
        *(short8*)(abuf + xr * SH + xc + 8) = *(const short8*)(gp + 8);
        __syncthreads();

        f32x4 oacc[2][2];
        #pragma unroll
        for (int s = 0; s < 2; s++) { oacc[s][0] = splat4(bo[s]); oacc[s][1] = splat4(bo[s]); }
        #pragma unroll
        for (int kt = 0; kt < 8; kt++) {
            short8 a0 = *(const short8*)(abuf + l15 * SH + kt * 32 + quad * 8);
            short8 a1 = *(const short8*)(abuf + (16 + l15) * SH + kt * 32 + quad * 8);
            #pragma unroll
            for (int s = 0; s < 2; s++) {
                oacc[s][0] = __builtin_amdgcn_mfma_f32_16x16x32_bf16(a0, wb[s][kt], oacc[s][0], 0, 0, 0);
                oacc[s][1] = __builtin_amdgcn_mfma_f32_16x16x32_bf16(a1, wb[s][kt], oacc[s][1], 0, 0, 0);
            }
        }

        // C-frag -> LDS (fp32), then full-row NT dwordx4 stores
        #pragma unroll
        for (int s = 0; s < 2; s++)
          #pragma unroll
          for (int mt = 0; mt < 2; mt++)
            #pragma unroll
            for (int r = 0; r < 4; r++)
                obuf[(mt * 16 + quad * 4 + r) * OSTR + w * 32 + s * 16 + l15] = oacc[s][mt][r];
        __syncthreads();
        {
            const int orow = tid >> 4;           // 0..31
            const int oseg = tid & 15;           // 16 x 64B segments
            float* op = out + (size_t)(m0 + orow) * F + oseg * 16;
            #pragma unroll
            for (int k = 0; k < 4; k++) {
                f32x4 v = *(const f32x4*)(obuf + orow * OSTR + oseg * 16 + k * 4);
                __builtin_nontemporal_store(v, (f32x4*)(op + k * 4));
            }
        }
        __syncthreads();   // obuf/abuf reuse safe for next chunk
    }
}

extern "C" void kernel_launch(void* const* d_in, const int* in_sizes, int n_in,
                              void* d_out, int out_size, void* d_ws, size_t ws_size,
                              hipStream_t stream)
{
    const float* x    = (const float*)d_in[0];
    const float* Wih  = (const float*)d_in[1];
    const float* Whh  = (const float*)d_in[2];
    const float* bih  = (const float*)d_in[3];
    const float* bhh  = (const float*)d_in[4];
    const float* c0   = (const float*)d_in[5];
    const float* Wout = (const float*)d_in[6];
    const float* bout = (const float*)d_in[7];
    const int* seqlen = (const int*)d_in[8];

    // workspace: packed weights + counters + bf16 h history (G, 2*out_size B)
    char* ws = (char*)d_ws;
    short* whh_p  = (short*)(ws);                   // 512 KB
    short* wih_hi = (short*)(ws + 512 * 1024);      // 512 KB
    short* wih_lo = (short*)(ws + 1024 * 1024);     // 512 KB
    short* wout_p = (short*)(ws + 1536 * 1024);     // 128 KB
    unsigned* ctr = (unsigned*)(ws + 1664 * 1024);  // 256 B
    short* G      = (short*)(ws + 1792 * 1024);     // out_size elems * 2 B
    (void)in_sizes; (void)n_in; (void)out_size; (void)ws_size;

    pack_kernel<<<160, 256, 0, stream>>>(Whh, Wih, Wout, whh_p, wih_hi, wih_lo,
                                         wout_p, ctr);
    lstm_rec<<<256, 512, 0, stream>>>(x, bih, bhh, c0,
                                      whh_p, wih_hi, wih_lo, seqlen, ctr, G);
    out_proj<<<1024, 512, 0, stream>>>(G, wout_p, bout, seqlen, (float*)d_out);
}

// Round 7
// 1750.904 us; speedup vs baseline: 2.0392x; 2.0392x over previous
//
#include <hip/hip_runtime.h>

typedef __attribute__((ext_vector_type(8))) short short8;   // 8 bf16 = 4 VGPRs (MFMA A/B frag)
typedef __attribute__((ext_vector_type(4))) float f32x4;    // MFMA C/D frag

#define F   256
#define SH  264   // LDS row stride in bf16 units: 528 B, 16B-aligned, <=2-way bank aliasing

__device__ __forceinline__ short f2bf(float f) {
    union { float f; unsigned u; } v; v.f = f;
    unsigned r = (v.u + 0x7fffu + ((v.u >> 16) & 1u)) >> 16;   // RTNE
    return (short)r;
}
__device__ __forceinline__ float bf2f(short s) {
    union { float f; unsigned u; } v; v.u = ((unsigned)(unsigned short)s) << 16;
    return v.f;
}
__device__ __forceinline__ float sigm(float x) {
    return __builtin_amdgcn_rcpf(1.f + __builtin_amdgcn_exp2f(-1.442695041f * x));
}
__device__ __forceinline__ float tanhx(float x) {
    return 1.f - 2.f * __builtin_amdgcn_rcpf(1.f + __builtin_amdgcn_exp2f(2.885390082f * x));
}
__device__ __forceinline__ f32x4 splat4(float v) {
    f32x4 r; r[0] = v; r[1] = v; r[2] = v; r[3] = v; return r;
}

// ---------------------------------------------------------------------------
// Pack: whh/wih (hi+lo split) in COL-BLOCK-SLICED MFMA-B order (R3/R6 layout,
// proven): dst = c*32768 + ((i*8+kt)*512 + lane*8), i = 2*gate + s, where
// n-tile nt -> gate = nt>>4, c = (nt&15)>>1, s = nt&1.
// wout in per-col-block-contiguous order (R5 layout, proven):
// dst = c*8192 + ((kt*2 + s)*512 + lane*8), nt = 2c + s.
// Zeroes the 32 per-row-group exchange counters.
// ---------------------------------------------------------------------------
__global__ void pack_kernel(const float* __restrict__ Whh, const float* __restrict__ Wih,
                            const float* __restrict__ Wout,
                            short* __restrict__ whh_p, short* __restrict__ wih_hi,
                            short* __restrict__ wih_lo, short* __restrict__ wout_p,
                            unsigned* __restrict__ ctr)
{
    int idx = blockIdx.x * blockDim.x + threadIdx.x;
    if (idx < 64) ctr[idx] = 0u;
    if (idx < 64 * 8 * 64) {                       // W_hh + W_ih: 64 n-tiles x 8 kt x 64 lanes
        int lane = idx & 63, kt = (idx >> 6) & 7, nt = idx >> 9;
        int n = nt * 16 + (lane & 15);
        int k = kt * 32 + (lane >> 4) * 8;
        int c = (nt & 15) >> 1;
        int i = ((nt >> 4) << 1) | (nt & 1);
        int dst = c * 32768 + ((i * 8 + kt) * 512 + lane * 8);
        const float* s1 = Whh + n * F + k;
        const float* s2 = Wih + n * F + k;
        #pragma unroll
        for (int j = 0; j < 8; j++) {
            whh_p[dst + j] = f2bf(s1[j]);
            float v = s2[j];
            short hi = f2bf(v);
            wih_hi[dst + j] = hi;
            wih_lo[dst + j] = f2bf(v - bf2f(hi));
        }
    } else {
        int i2 = idx - 64 * 8 * 64;
        if (i2 < 16 * 8 * 64) {                    // W_out: 16 n-tiles
            int lane = i2 & 63, kt = (i2 >> 6) & 7, nt = i2 >> 9;
            int n = nt * 16 + (lane & 15);
            int k = kt * 32 + (lane >> 4) * 8;
            int c = nt >> 1, s = nt & 1;
            int dst = c * 8192 + ((kt * 2 + s) * 512 + lane * 8);
            const float* sp = Wout + n * F + k;
            #pragma unroll
            for (int j = 0; j < 8; j++) wout_p[dst + j] = f2bf(sp[j]);
        }
    }
}

// Load a wave's 32 B-fragments (4 gates x 8 kt, its cw half of 32 cols).
__device__ __forceinline__ void load_wb(short8 (&wb)[4][8], const short* __restrict__ base,
                                        int cw, int lane)
{
    #pragma unroll
    for (int g = 0; g < 4; g++)
        #pragma unroll
        for (int kt = 0; kt < 8; kt++)
            wb[g][kt] = *(const short8*)(base + (((2 * g + cw) * 8 + kt) * 512 + lane * 8));
}

// acc[g][mt] += A(rows rw*32 + mt*16, from LDS) x wb[g][kt] over K=256.
__device__ __forceinline__ void mm_reg(f32x4 (&acc)[4][2], const short8 (&wb)[4][8],
                                       const short* hb, int rw, int l15, int quad)
{
    #pragma unroll
    for (int kt = 0; kt < 8; kt++) {
        short8 a0 = *(const short8*)(hb + (rw * 32 + l15) * SH + kt * 32 + quad * 8);
        short8 a1 = *(const short8*)(hb + (rw * 32 + 16 + l15) * SH + kt * 32 + quad * 8);
        #pragma unroll
        for (int g = 0; g < 4; g++) {
            acc[g][0] = __builtin_amdgcn_mfma_f32_16x16x32_bf16(a0, wb[g][kt], acc[g][0], 0, 0, 0);
            acc[g][1] = __builtin_amdgcn_mfma_f32_16x16x32_bf16(a1, wb[g][kt], acc[g][1], 0, 0, 0);
        }
    }
}

// ---------------------------------------------------------------------------
// Weights-stationary recurrence, fence-free exchange, fused out-projection.
// 256 blocks (1/CU, co-resident; 90 KB LDS forces 1/CU) = 32 row-groups x
// 8 col-blocks.  Block (rg,c): 128 rows x 32 h-cols.  W_hh slice pinned in
// regs for all T steps (zero steady-state weight traffic).  Per step:
//   mfma -> cell -> h chunk to G[parity] (2x u64 relaxed agent atomic stores)
//   -> __syncthreads (vmcnt drain) -> release add + spin + acquire (R3-proven,
//   NO standalone fences -> no L2 flush) -> 16x u64 relaxed atomic loads of
//   full 256-col slice -> hbuf -> out-proj (16 MFMA, LDS W_out) -> NT stores.
// Parity double-buffer is WAR-safe: barrier bounds intra-group skew to 1 step.
// ---------------------------------------------------------------------------
__global__ __launch_bounds__(512, 2)
void lstm_rec(const float* __restrict__ x, const float* __restrict__ b_ih,
              const float* __restrict__ b_hh, const float* __restrict__ c0,
              const float* __restrict__ b_out,
              const short* __restrict__ whh_p, const short* __restrict__ wih_hi,
              const short* __restrict__ wih_lo, const short* __restrict__ wout_p,
              const int* __restrict__ seqlen, unsigned* __restrict__ ctr,
              short* __restrict__ G, float* __restrict__ out)
{
    __shared__ short hbuf[128 * SH];     // 67.6 KB: row-group's full h (128 x 256)
    __shared__ short hstage[128 * 32];   //  8.2 KB: own h chunk, row-major
    __shared__ short wlout[8192];        // 16.4 KB: W_out slice (32 cols) -> 92 KB total
    const int T    = *seqlen;
    const int tid  = threadIdx.x;
    const int lane = tid & 63;
    const int wv   = tid >> 6;           // wave 0..7
    const int rw   = wv >> 1;            // row-wave 0..3 (32 rows each)
    const int cw   = wv & 1;             // col-wave 0..1 (16 cols each)
    const int l15  = lane & 15;
    const int quad = lane >> 4;
    const int c    = blockIdx.x & 7;     // col-block 0..7
    const int rg   = blockIdx.x >> 3;    // row-group 0..31
    const int row0 = rg * 128;

    // ---- stage W_out slice -> LDS (16 shorts/thread) ----
    {
        const short* src = wout_p + c * 8192;
        *(short8*)(wlout + tid * 16)     = *(const short8*)(src + tid * 16);
        *(short8*)(wlout + tid * 16 + 8) = *(const short8*)(src + tid * 16 + 8);
    }

    // staging geometry: thread covers row xr, 4-elem col chunks
    const int xr = tid >> 2;             // 0..127
    const int xq = (tid & 3) * 4;

    // ---- x_proj = x @ W_ih^T (+biases), fp32-exact via 3-term split bf16 ----
    f32x4 xpj[4][2];
    #pragma unroll
    for (int g = 0; g < 4; g++) { xpj[g][0] = splat4(0.f); xpj[g][1] = splat4(0.f); }

    short8 wb[4][8];

    {   // stage x_lo
        const float* xp = x + (size_t)(row0 + xr) * F;
        #pragma unroll
        for (int j = 0; j < 16; j++) {
            f32x4 v = *(const f32x4*)(xp + xq + j * 16);
            #pragma unroll
            for (int e = 0; e < 4; e++) {
                short hi = f2bf(v[e]);
                hbuf[xr * SH + xq + j * 16 + e] = f2bf(v[e] - bf2f(hi));
            }
        }
    }
    load_wb(wb, wih_hi + c * 32768, cw, lane);
    __syncthreads();
    mm_reg(xpj, wb, hbuf, rw, l15, quad);          // x_lo x Wih_hi
    __syncthreads();
    {   // stage x_hi (stays as h_0)
        const float* xp = x + (size_t)(row0 + xr) * F;
        #pragma unroll
        for (int j = 0; j < 16; j++) {
            f32x4 v = *(const f32x4*)(xp + xq + j * 16);
            #pragma unroll
            for (int e = 0; e < 4; e++)
                hbuf[xr * SH + xq + j * 16 + e] = f2bf(v[e]);
        }
    }
    __syncthreads();
    mm_reg(xpj, wb, hbuf, rw, l15, quad);          // x_hi x Wih_hi
    load_wb(wb, wih_lo + c * 32768, cw, lane);
    mm_reg(xpj, wb, hbuf, rw, l15, quad);          // x_hi x Wih_lo

    // ---- persistent W_hh fragments, pinned (asm is now the definer) ----
    load_wb(wb, whh_p + c * 32768, cw, lane);
    #pragma unroll
    for (int g = 0; g < 4; g++)
        #pragma unroll
        for (int kt = 0; kt < 8; kt++)
            asm volatile("" : "+v"(wb[g][kt]));

    // biases (b_ih + b_hh), per gate column
    const int mycol = c * 32 + cw * 16 + l15;
    #pragma unroll
    for (int g = 0; g < 4; g++) {
        float bias = b_ih[g * 256 + mycol] + b_hh[g * 256 + mycol];
        #pragma unroll
        for (int mt = 0; mt < 2; mt++)
            #pragma unroll
            for (int r = 0; r < 4; r++) xpj[g][mt][r] += bias;
    }

    // cell state init (c0 broadcast over rows) + out bias + out row offsets
    float cst[2][4];
    {
        float cv = c0[mycol];
        #pragma unroll
        for (int mt = 0; mt < 2; mt++)
            #pragma unroll
            for (int r = 0; r < 4; r++) cst[mt][r] = cv;
    }
    const float bo = b_out[mycol];
    int rowoff[2][4];                    // (row)*T*F + mycol, 32-bit (max ~52M)
    #pragma unroll
    for (int mt = 0; mt < 2; mt++)
        #pragma unroll
        for (int r = 0; r < 4; r++)
            rowoff[mt][r] = (row0 + rw * 32 + mt * 16 + quad * 4 + r) * T * F + mycol;

    const int grow = tid >> 2;           // G dump/read geometry
    const int gch  = tid & 3;

    for (int t = 0; t < T; t++) {
        // gates = x_proj + h_t @ W_hh^T  (B from pinned regs, A from LDS)
        f32x4 acc[4][2];
        #pragma unroll
        for (int g = 0; g < 4; g++) { acc[g][0] = xpj[g][0]; acc[g][1] = xpj[g][1]; }
        mm_reg(acc, wb, hbuf, rw, l15, quad);

        // cell update (fp32); own h chunk -> hstage (row-major 128x32)
        #pragma unroll
        for (int mt = 0; mt < 2; mt++)
          #pragma unroll
          for (int r = 0; r < 4; r++) {
            float ig = sigm(acc[0][mt][r]);
            float fg = sigm(acc[1][mt][r]);
            float gg = tanhx(acc[2][mt][r]);
            float og = sigm(acc[3][mt][r]);
            float cn = fg * cst[mt][r] + ig * gg;
            cst[mt][r] = cn;
            hstage[(rw * 32 + mt * 16 + quad * 4 + r) * 32 + cw * 16 + l15]
                = f2bf(og * tanhx(cn));
          }
        __syncthreads();   // hstage complete; hbuf no longer read

        // dump chunk -> G[parity(t+1)], 2x u64 relaxed agent atomic stores
        const size_t par = ((size_t)(t + 1) & 1) << 20;   // 4096*256 shorts
        {
            const unsigned long long* hs =
                (const unsigned long long*)(hstage + grow * 32 + gch * 8);
            unsigned long long* gd = (unsigned long long*)
                (G + par + (size_t)(row0 + grow) * 256 + c * 32 + gch * 8);
            __hip_atomic_store(gd,     hs[0], __ATOMIC_RELAXED, __HIP_MEMORY_SCOPE_AGENT);
            __hip_atomic_store(gd + 1, hs[1], __ATOMIC_RELAXED, __HIP_MEMORY_SCOPE_AGENT);
        }
        __syncthreads();   // compiler-emitted vmcnt(0) drains every wave's stores

        // group barrier: 8 col-blocks of this row-group (monotonic, bounded)
        if (tid == 0) {
            __hip_atomic_fetch_add(&ctr[rg], 1u, __ATOMIC_RELEASE,
                                   __HIP_MEMORY_SCOPE_AGENT);
            unsigned tgt = 8u * (unsigned)(t + 1);
            int guard = 1 << 20;
            while (__hip_atomic_load(&ctr[rg], __ATOMIC_RELAXED,
                                     __HIP_MEMORY_SCOPE_AGENT) < tgt && --guard)
                __builtin_amdgcn_s_sleep(1);
            (void)__hip_atomic_load(&ctr[rg], __ATOMIC_ACQUIRE,
                                    __HIP_MEMORY_SCOPE_AGENT);
        }
        __syncthreads();

        // read back full 256-col slice of h_{t+1} -> hbuf (16x u64 atomic loads)
        {
            const short* gp = G + par + (size_t)(row0 + grow) * 256 + gch * 64;
            #pragma unroll
            for (int k = 0; k < 16; k++) {
                unsigned long long v = __hip_atomic_load(
                    (const unsigned long long*)(gp + k * 4),
                    __ATOMIC_RELAXED, __HIP_MEMORY_SCOPE_AGENT);
                *(unsigned long long*)(hbuf + grow * SH + gch * 64 + k * 4) = v;
            }
        }
        __syncthreads();

        // fused out-projection: out[.,t,.] = h_{t+1} @ W_out^T + b_out
        f32x4 oacc[2];
        oacc[0] = splat4(bo); oacc[1] = splat4(bo);
        #pragma unroll
        for (int kt = 0; kt < 8; kt++) {
            short8 a0 = *(const short8*)(hbuf + (rw * 32 + l15) * SH + kt * 32 + quad * 8);
            short8 a1 = *(const short8*)(hbuf + (rw * 32 + 16 + l15) * SH + kt * 32 + quad * 8);
            short8 b  = *(const short8*)(wlout + (kt * 2 + cw) * 512 + lane * 8);
            oacc[0] = __builtin_amdgcn_mfma_f32_16x16x32_bf16(a0, b, oacc[0], 0, 0, 0);
            oacc[1] = __builtin_amdgcn_mfma_f32_16x16x32_bf16(a1, b, oacc[1], 0, 0, 0);
        }
        {
            float* op = out + (size_t)t * F;
            #pragma unroll
            for (int mt = 0; mt < 2; mt++)
                #pragma unroll
                for (int r = 0; r < 4; r++)
                    __builtin_nontemporal_store(oacc[mt][r], op + rowoff[mt][r]);
        }
        // no extra sync: hbuf next written after two barriers next iteration
    }
}

extern "C" void kernel_launch(void* const* d_in, const int* in_sizes, int n_in,
                              void* d_out, int out_size, void* d_ws, size_t ws_size,
                              hipStream_t stream)
{
    const float* x    = (const float*)d_in[0];
    const float* Wih  = (const float*)d_in[1];
    const float* Whh  = (const float*)d_in[2];
    const float* bih  = (const float*)d_in[3];
    const float* bhh  = (const float*)d_in[4];
    const float* c0   = (const float*)d_in[5];
    const float* Wout = (const float*)d_in[6];
    const float* bout = (const float*)d_in[7];
    const int* seqlen = (const int*)d_in[8];

    // workspace: packed weights + counters + 2x2MB h parity buffers
    char* ws = (char*)d_ws;
    short* whh_p  = (short*)(ws);                   // 512 KB
    short* wih_hi = (short*)(ws + 512 * 1024);      // 512 KB
    short* wih_lo = (short*)(ws + 1024 * 1024);     // 512 KB
    short* wout_p = (short*)(ws + 1536 * 1024);     // 128 KB
    unsigned* ctr = (unsigned*)(ws + 1664 * 1024);  // 256 B
    short* G      = (short*)(ws + 1792 * 1024);     // 2 x 2 MB
    (void)in_sizes; (void)n_in; (void)out_size; (void)ws_size;

    pack_kernel<<<160, 256, 0, stream>>>(Whh, Wih, Wout, whh_p, wih_hi, wih_lo,
                                         wout_p, ctr);
    lstm_rec<<<256, 512, 0, stream>>>(x, bih, bhh, c0, bout,
                                      whh_p, wih_hi, wih_lo, wout_p,
                                      seqlen, ctr, G, (float*)d_out);
}